// Round 13
// baseline (3378.494 us; speedup 1.0000x reference)
//
#include <hip/hip_runtime.h>
#include <hip/hip_bf16.h>

// ---------------- problem constants ----------------
constexpr int Bn = 64;
constexpr int Tn = 512;

using bf16x8 = __attribute__((ext_vector_type(8))) short;
using f32x4  = __attribute__((ext_vector_type(4))) float;
typedef unsigned long long u64;

// ---------------- ws layout (byte offsets) ----------------
// Tagged state u32 = (bf16 << 16) | tag16. tag(state of step τ) = τ+1; initial (τ=-1) = 0.
constexpr size_t OFF_H1    = 0;                       // u32 [2][64][512] blended h1 ping-pong
constexpr size_t OFF_NH1   = OFF_H1  + 262144;        // u32 [16][64][512] nh1 (16-deep)
constexpr size_t OFF_H2S   = OFF_NH1 + 2097152;       // u32 [2][64][512] blended h2
constexpr size_t OFF_L2P   = OFF_H2S + 262144;        // int [4][16][32] L2 consume-progress
constexpr size_t OFF_BIASP = OFF_L2P + 8192;          // f32 [2][2048] permuted biases
constexpr size_t OFF_H2ALL = OFF_BIASP + 16384;       // bf16 [32768][512]
constexpr size_t OFF_X1    = OFF_H2ALL + 33554432;    // bf16 [32768][512]
constexpr size_t OFF_XPAD  = OFF_X1 + 33554432;       // bf16 [512][64][32]
constexpr size_t OFF_W1P   = OFF_XPAD + 2097152;      // bf16 [64][17][2][64][8]
constexpr size_t OFF_W2P   = OFF_W1P + 2228224;       // bf16 [64][32][2][64][8]
constexpr size_t OFF_WD1P  = OFF_W2P + 4194304;       // bf16 [32][16][64][8]
constexpr size_t OFF_WD2P  = OFF_WD1P + 524288;       // bf16 [32][16][64][8]
constexpr size_t OFF_WD3P  = OFF_WD2P + 524288;       // bf16 [16][16][64][8]
constexpr size_t OFF_PART  = OFF_WD3P + 262144;       // f32 [8192] loss partials
constexpr size_t WS_NEED   = OFF_PART + 32768;        // ~76 MB

__device__ __forceinline__ float sigf(float x) { return 1.f / (1.f + expf(-x)); }
__device__ __forceinline__ unsigned short f2b(float x) {
    __hip_bfloat16 h = __float2bfloat16(x);
    return *reinterpret_cast<unsigned short*>(&h);
}
__device__ __forceinline__ float b2f(unsigned short u) {
    unsigned v = ((unsigned)u) << 16;
    return *reinterpret_cast<float*>(&v);
}
__device__ __forceinline__ f32x4 mfma16(bf16x8 a, bf16x8 b, f32x4 c) {
    return __builtin_amdgcn_mfma_f32_16x16x32_bf16(a, b, c, 0, 0, 0);
}

// agent-scope relaxed atomics (R4-R12-proven primitives)
__device__ __forceinline__ unsigned ldu(const unsigned* p) {
    return __hip_atomic_load(p, __ATOMIC_RELAXED, __HIP_MEMORY_SCOPE_AGENT);
}
__device__ __forceinline__ void stu(unsigned* p, unsigned v) {
    __hip_atomic_store(p, v, __ATOMIC_RELAXED, __HIP_MEMORY_SCOPE_AGENT);
}
__device__ __forceinline__ int ldi(const int* p) {
    return __hip_atomic_load(p, __ATOMIC_RELAXED, __HIP_MEMORY_SCOPE_AGENT);
}
__device__ __forceinline__ void sti(int* p, int v) {
    __hip_atomic_store(p, v, __ATOMIC_RELAXED, __HIP_MEMORY_SCOPE_AGENT);
}
// block barrier for LDS reuse WITHOUT draining vmem (no implicit vmcnt(0)):
// producers' tagged stores stay in flight; consumers self-validate via tags.
__device__ __forceinline__ void block_sync_lds() {
    asm volatile("s_waitcnt lgkmcnt(0)" ::: "memory");
    __builtin_amdgcn_sched_barrier(0);
    __builtin_amdgcn_s_barrier();
}

// ---------------- one-time prep ----------------
constexpr int PN0 = 139264;            // W1P ushort8 items
constexpr int PN1 = PN0 + 262144;      // W2P
constexpr int PN2 = PN1 + 4096;        // BIASP f32 items
constexpr int PN3 = PN2 + 131072;      // XPAD ushort8
constexpr int PN4 = PN3 + 32768;       // WD1P ushort8
constexpr int PN5 = PN4 + 32768;       // WD2P
constexpr int PN6 = PN5 + 16384;       // WD3P
constexpr int PN7 = PN6 + 164352;      // zero H1+NH1+H2S+L2P (float4 items)

__global__ __launch_bounds__(256) void prep_kernel(
    const float* __restrict__ seq_in,
    const float* __restrict__ W1, const float* __restrict__ b1,
    const float* __restrict__ W2, const float* __restrict__ b2,
    const float* __restrict__ Wd1, const float* __restrict__ Wd2,
    const float* __restrict__ Wd3, char* __restrict__ ws)
{
    const int idx = blockIdx.x * 256 + threadIdx.x;
    if (idx >= PN7) return;
    if (idx < PN0) {                       // W1P: [np][kk(17)][half][lane][8]
        const int lane = idx & 63; int r = idx >> 6;
        const int half = r & 1; r >>= 1;
        const int kk = r % 17, np = r / 17;
        const int colg = (np*2 + half)*16 + (lane & 15);
        const int oc = (colg & 3)*512 + (colg >> 2);
        const int lg = lane >> 4;
        short v[8];
        #pragma unroll
        for (int j = 0; j < 8; ++j) {
            float x;
            if (kk < 16) x = W1[(size_t)(6 + kk*32 + lg*8 + j) * 2048 + oc];
            else { const int rr = lg*8 + j; x = (rr < 6) ? W1[(size_t)rr * 2048 + oc] : 0.f; }
            v[j] = (short)f2b(x);
        }
        bf16x8* dst = (bf16x8*)((unsigned short*)(ws + OFF_W1P) + ((size_t)(np*17 + kk)*2 + half)*512 + lane*8);
        *dst = *(bf16x8*)v;
    } else if (idx < PN1) {                // W2P: [np][kk(32)][half][lane][8]
        const int i = idx - PN0;
        const int lane = i & 63; int r = i >> 6;
        const int half = r & 1; r >>= 1;
        const int kk = r & 31, np = r >> 5;
        const int colg = (np*2 + half)*16 + (lane & 15);
        const int oc = (colg & 3)*512 + (colg >> 2);
        const int lg = lane >> 4;
        short v[8];
        #pragma unroll
        for (int j = 0; j < 8; ++j)
            v[j] = (short)f2b(W2[(size_t)(kk*32 + lg*8 + j) * 2048 + oc]);
        bf16x8* dst = (bf16x8*)((unsigned short*)(ws + OFF_W2P) + ((size_t)(np*32 + kk)*2 + half)*512 + lane*8);
        *dst = *(bf16x8*)v;
    } else if (idx < PN2) {                // BIASP (gate-permuted)
        const int i = idx - PN1;
        const int layer = i >> 11, colg = i & 2047;
        const float* bb = layer ? b2 : b1;
        ((float*)(ws + OFF_BIASP))[i] = bb[(colg & 3)*512 + (colg >> 2)];
    } else if (idx < PN3) {                // XPAD [t][b][32]
        const int i = idx - PN2;
        const int sub = i & 3, tb = i >> 2;
        const int t = tb >> 6, b = tb & 63;
        short v[8];
        #pragma unroll
        for (int j = 0; j < 8; ++j) {
            const int rr = sub*8 + j;
            v[j] = (short)f2b(rr < 6 ? seq_in[((size_t)b*Tn + t)*6 + rr] : 0.f);
        }
        bf16x8* dst = (bf16x8*)((unsigned short*)(ws + OFF_XPAD) + (size_t)tb*32 + sub*8);
        *dst = *(bf16x8*)v;
    } else if (idx < PN6) {                // WD1P / WD2P / WD3P: [np][kk(16)][lane][8]
        int i; const float* Wd; size_t dsto; int N;
        if (idx < PN4)      { i = idx - PN3; Wd = Wd1; dsto = OFF_WD1P; N = 512; }
        else if (idx < PN5) { i = idx - PN4; Wd = Wd2; dsto = OFF_WD2P; N = 512; }
        else                { i = idx - PN5; Wd = Wd3; dsto = OFF_WD3P; N = 256; }
        const int lane = i & 63; const int r = i >> 6;
        const int kk = r & 15, np = r >> 4;
        const int col = np*16 + (lane & 15);
        const int lg = lane >> 4;
        short v[8];
        #pragma unroll
        for (int j = 0; j < 8; ++j)
            v[j] = (short)f2b(Wd[(size_t)(kk*32 + lg*8 + j) * N + col]);
        bf16x8* dst = (bf16x8*)((unsigned short*)(ws + dsto) + ((size_t)(np*16 + kk)*64 + lane)*8);
        *dst = *(bf16x8*)v;
    } else {                               // zero all tagged state + progress (CRITICAL for replay)
        const int i = idx - PN6;
        ((float4*)(ws + OFF_H1))[i] = make_float4(0.f, 0.f, 0.f, 0.f);
    }
}

// ---------------- persistent recurrence kernel ----------------
// 128 blocks x 512 threads (8 waves). Blocks 0..63: L1; 64..127: L2.
// mt = vb>>4 (batch 16-row group), ng = vb&15; wave w owns col-tile nt = ng*8+w.
// Sync: DATA-EMBEDDED TAGS, drain-free. Producers store tagged u32 state and
// NEVER drain (in-loop barriers are raw s_barrier + lgkmcnt only — no vmcnt).
// Consumers spin on ONE tagged word (4B/RT traffic), then load+verify the rest.
// H1/H2S: 2-slot ping-pong (overwrite-safe by tag-ordering induction, proven
// correct in R9); NH1: 16-deep + lazy back-pressure counter every 8 steps.
constexpr int FRAGS = 520;   // ushort stride per kk slot (1040 B)

__global__ __launch_bounds__(512, 1) void persist_kernel(const int* __restrict__ lens,
                                                         char* __restrict__ ws)
{
    __shared__ unsigned short afrag[33 * FRAGS];
    __shared__ float sc[8][16][17];

    const int tid = threadIdx.x;
    const int l = tid & 63, w = tid >> 6;
    const int blk = blockIdx.x;
    const bool isL1 = (blk < 64);
    const int vb = isL1 ? blk : blk - 64;
    const int mt = vb >> 4;
    const int ng = vb & 15;
    const int nt = ng * 8 + w;
    const int np = nt >> 1, half = nt & 1;
    const int lr = l & 15, lg = l >> 4;

    unsigned* H1  = (unsigned*)(ws + OFF_H1);
    unsigned* NH1 = (unsigned*)(ws + OFF_NH1);
    unsigned* H2S = (unsigned*)(ws + OFF_H2S);
    int* l2prog   = (int*)(ws + OFF_L2P);
    const float* biasp = (const float*)(ws + OFF_BIASP);
    u64* h2bu = (u64*)(ws + OFF_H2ALL);
    const unsigned short* XP = (const unsigned short*)(ws + OFF_XPAD);

    // ---- private W slice in VGPRs for all 512 steps ----
    bf16x8 wreg[32];
    if (isL1) {
        const unsigned short* Bp = (const unsigned short*)(ws + OFF_W1P)
                                 + ((size_t)(np*17)*2 + half)*512 + l*8;
        #pragma unroll
        for (int kk = 0; kk < 17; ++kk) wreg[kk] = *(const bf16x8*)(Bp + (size_t)kk*1024);
    } else {
        const unsigned short* Bp = (const unsigned short*)(ws + OFF_W2P)
                                 + ((size_t)(np*32)*2 + half)*512 + l*8;
        #pragma unroll
        for (int kk = 0; kk < 32; ++kk) wreg[kk] = *(const bf16x8*)(Bp + (size_t)kk*1024);
    }

    const int myb = mt*16 + lr;
    const int myd = nt*4 + lg;
    const int mylen = lens[myb];
    const float biascol = biasp[(isL1 ? 0 : 2048) + nt*16 + lr];
    float c_reg = 0.f, h_reg = 0.f;

    if (isL1) {
        const int q = tid & 127;           // my dim-quad (u32 cols q*4..q*4+3)
        const int r0 = tid >> 7;           // rows r0 + it*4
        const int kk = q >> 3, sub = (q >> 1) & 3, hf = q & 1;
        const int* bpp = l2prog + (mt*16 + (tid & 15))*32;
        for (int t = 0; t < Tn; ++t) {
            // x-part staging (no dependence)
            if (tid < 64) {
                const int r = tid >> 2, lgg = tid & 3;
                bf16x8 xv = *(const bf16x8*)(XP + ((size_t)t*64 + mt*16 + r)*32 + lgg*8);
                *(bf16x8*)(afrag + 16*FRAGS + (lgg*16 + r)*8) = xv;
            }
            // lazy back-pressure every 8 steps: all L2 consumed nh1(t-8)
            // => writes t..t+7 overwrite slots t-16..t-9: all consumed (monotone)
            if ((t & 7) == 0 && tid < 16) { while (ldi(bpp) < t - 8) {} }
            // ---- tag-poll: 1-word spin, then load-all + verify ----
            const unsigned etag = (unsigned)t;
            const unsigned* srcq = H1 + ((t+1)&1)*32768 + (size_t)(mt*16)*512 + q*4;
            const unsigned* p0 = srcq + (size_t)r0*512;
            while ((ldu(p0) ^ etag) & 0xffffu) {}          // cheap spin (4B/RT)
            unsigned v[4][4];
            for (;;) {
                #pragma unroll
                for (int it = 0; it < 4; ++it) {
                    const unsigned* p = srcq + (size_t)(r0 + it*4)*512;
                    v[it][0] = ldu(p);   v[it][1] = ldu(p+1);
                    v[it][2] = ldu(p+2); v[it][3] = ldu(p+3);
                }
                unsigned bad = 0;
                #pragma unroll
                for (int it = 0; it < 4; ++it)
                    bad |= (v[it][0]^etag)|(v[it][1]^etag)|(v[it][2]^etag)|(v[it][3]^etag);
                if (!(bad & 0xffffu)) break;
            }
            #pragma unroll
            for (int it = 0; it < 4; ++it) {
                const unsigned lo = (v[it][1] & 0xffff0000u) | (v[it][0] >> 16);
                const unsigned hi = (v[it][3] & 0xffff0000u) | (v[it][2] >> 16);
                *(u64*)(afrag + kk*FRAGS + (sub*16 + r0 + it*4)*8 + hf*4) = ((u64)hi << 32) | lo;
            }
            block_sync_lds();

            f32x4 acc = {0.f,0.f,0.f,0.f};
            const unsigned short* ap = afrag + l*8;
            #pragma unroll
            for (int kk2 = 0; kk2 < 17; ++kk2)
                acc = mfma16(*(const bf16x8*)(ap + kk2*FRAGS), wreg[kk2], acc);

            #pragma unroll
            for (int i = 0; i < 4; ++i) sc[w][lg*4 + i][lr] = acc[i] + biascol;
            asm volatile("s_waitcnt lgkmcnt(0)" ::: "memory");

            const float gi = sc[w][lr][lg*4+0], gj = sc[w][lr][lg*4+1];
            const float gf = sc[w][lr][lg*4+2], go = sc[w][lr][lg*4+3];
            const float m = (t < mylen) ? 1.f : 0.f;
            const float cnew = c_reg*sigf(gf + 1.f) + sigf(gi)*tanhf(gj);
            c_reg = m*cnew + (1.f - m)*c_reg;
            const float nh = tanhf(cnew)*sigf(go);
            const float hb = m*nh + (1.f - m)*h_reg;
            h_reg = hb;

            // publish tagged values — NO drain, tags carry ordering
            stu(H1 + (t&1)*32768 + (size_t)myb*512 + myd,
                ((unsigned)f2b(hb) << 16) | (unsigned)(t+1));
            stu(NH1 + (t&15)*32768 + (size_t)myb*512 + myd,
                ((unsigned)f2b(nh) << 16) | (unsigned)(t+1));
            block_sync_lds();   // afrag/sc reuse fence (no vmcnt drain)
        }
    } else {
        const int q = tid & 255;           // q<128: nh1 quad q; else h2 quad q-128
        const int r0 = tid >> 8;           // rows r0 + it*2
        const int kk = q >> 3, sub = (q >> 1) & 3, hf = q & 1;
        for (int s = 0; s < Tn; ++s) {
            const unsigned etag = (q < 128) ? (unsigned)(s+1) : (unsigned)s;
            const unsigned* srcq = (q < 128)
                ? (NH1 + (s&15)*32768 + (size_t)(mt*16)*512 + q*4)
                : (H2S + ((s+1)&1)*32768 + (size_t)(mt*16)*512 + (q-128)*4);
            const unsigned* p0 = srcq + (size_t)r0*512;
            while ((ldu(p0) ^ etag) & 0xffffu) {}          // cheap spin
            unsigned v[8][4];
            for (;;) {
                #pragma unroll
                for (int it = 0; it < 8; ++it) {
                    const unsigned* p = srcq + (size_t)(r0 + it*2)*512;
                    v[it][0] = ldu(p);   v[it][1] = ldu(p+1);
                    v[it][2] = ldu(p+2); v[it][3] = ldu(p+3);
                }
                unsigned bad = 0;
                #pragma unroll
                for (int it = 0; it < 8; ++it)
                    bad |= (v[it][0]^etag)|(v[it][1]^etag)|(v[it][2]^etag)|(v[it][3]^etag);
                if (!(bad & 0xffffu)) break;
            }
            #pragma unroll
            for (int it = 0; it < 8; ++it) {
                const unsigned lo = (v[it][1] & 0xffff0000u) | (v[it][0] >> 16);
                const unsigned hi = (v[it][3] & 0xffff0000u) | (v[it][2] >> 16);
                *(u64*)(afrag + kk*FRAGS + (sub*16 + r0 + it*2)*8 + hf*4) = ((u64)hi << 32) | lo;
            }
            block_sync_lds();
            if (tid == 0) sti(l2prog + (mt*16 + ng)*32, s + 1);  // consumed nh1(s)

            f32x4 acc = {0.f,0.f,0.f,0.f};
            const unsigned short* ap = afrag + l*8;
            #pragma unroll
            for (int kk2 = 0; kk2 < 32; ++kk2)
                acc = mfma16(*(const bf16x8*)(ap + kk2*FRAGS), wreg[kk2], acc);

            #pragma unroll
            for (int i = 0; i < 4; ++i) sc[w][lg*4 + i][lr] = acc[i] + biascol;
            asm volatile("s_waitcnt lgkmcnt(0)" ::: "memory");

            const float gi = sc[w][lr][lg*4+0], gj = sc[w][lr][lg*4+1];
            const float gf = sc[w][lr][lg*4+2], go = sc[w][lr][lg*4+3];
            const float m = (s < mylen) ? 1.f : 0.f;
            const float cnew = c_reg*sigf(gf + 1.f) + sigf(gi)*tanhf(gj);
            c_reg = m*cnew + (1.f - m)*c_reg;
            const float nh = tanhf(cnew)*sigf(go);
            const float hb = m*nh + (1.f - m)*h_reg;
            h_reg = hb;

            stu(H2S + (s&1)*32768 + (size_t)myb*512 + myd,
                ((unsigned)f2b(hb) << 16) | (unsigned)(s+1));
            // head input (plain cached, packed)
            const int pv = (int)f2b(m*nh);
            const int p0s = __shfl(pv, lr), p1s = __shfl(pv, lr+16),
                      p2s = __shfl(pv, lr+32), p3s = __shfl(pv, lr+48);
            if (lg == 0) {
                u64 npk = (u64)(unsigned)((p0s & 0xffff) | ((p1s & 0xffff) << 16))
                        | ((u64)(unsigned)((p2s & 0xffff) | ((p3s & 0xffff) << 16)) << 32);
                h2bu[((size_t)myb*Tn + s)*128 + nt] = npk;
            }
            block_sync_lds();   // afrag/sc reuse fence (no vmcnt drain)
        }
    }
}

// ---------------- head GEMM: C = relu(A[M,512]bf16 @ WP + bias) -> bf16 ----------------
__global__ __launch_bounds__(256) void hgemm_kernel(
    const unsigned short* __restrict__ A, const unsigned short* __restrict__ WP,
    const float* __restrict__ bias, unsigned short* __restrict__ C, int N)
{
    __shared__ unsigned short tr[4][16][24];
    const int tid = threadIdx.x;
    const int l = tid & 63, w = tid >> 6;
    const int np = blockIdx.x * 4 + w;
    const int colbase = np * 16;
    const int lr = l & 15, lg = l >> 4;

    bf16x8 wfr[16];
    #pragma unroll
    for (int kk = 0; kk < 16; ++kk)
        wfr[kk] = *(const bf16x8*)(WP + ((size_t)(np*16 + kk)*64 + l)*8);
    const float bv = bias[colbase + lr];

    for (int i = 0; i < 8; ++i) {
        const int rt = blockIdx.y * 8 + i;
        const unsigned short* ap = A + (size_t)(rt*16 + lr)*512 + lg*8;
        f32x4 acc = {0.f,0.f,0.f,0.f};
        #pragma unroll
        for (int kk = 0; kk < 16; ++kk)
            acc = mfma16(*(const bf16x8*)(ap + kk*32), wfr[kk], acc);
        #pragma unroll
        for (int j = 0; j < 4; ++j)
            tr[w][lg*4 + j][lr] = f2b(fmaxf(acc[j] + bv, 0.f));
        asm volatile("s_waitcnt lgkmcnt(0)" ::: "memory");
        if (lg == 0) {
            bf16x8 r0 = *(const bf16x8*)&tr[w][lr][0];
            bf16x8 r1 = *(const bf16x8*)&tr[w][lr][8];
            unsigned short* cp = C + (size_t)(rt*16 + lr)*N + colbase;
            *(bf16x8*)cp = r0;
            *(bf16x8*)(cp + 8) = r1;
        }
        asm volatile("s_waitcnt lgkmcnt(0)" ::: "memory");
    }
}

// ---------------- final layer + loss partials ----------------
__global__ __launch_bounds__(256) void d4_kernel(
    const unsigned short* __restrict__ X3, const float* __restrict__ W,
    const float* __restrict__ bias, const float* __restrict__ tgt,
    const int* __restrict__ lens, float* __restrict__ out,
    float* __restrict__ partials)
{
    __shared__ float pr[4];
    const int lane = threadIdx.x & 63;
    const int rr = threadIdx.x >> 6;
    const size_t r = (size_t)blockIdx.x * 4 + rr;
    const u64 xv = *(const u64*)(X3 + r * 256 + lane * 4);
    const float x0 = b2f((unsigned short)(xv & 0xffff));
    const float x1 = b2f((unsigned short)((xv >> 16) & 0xffff));
    const float x2 = b2f((unsigned short)((xv >> 32) & 0xffff));
    const float x3 = b2f((unsigned short)((xv >> 48) & 0xffff));
    const float4 w0 = *reinterpret_cast<const float4*>(W + (size_t)(lane*4 + 0) * 4);
    const float4 w1 = *reinterpret_cast<const float4*>(W + (size_t)(lane*4 + 1) * 4);
    const float4 w2 = *reinterpret_cast<const float4*>(W + (size_t)(lane*4 + 2) * 4);
    const float4 w3 = *reinterpret_cast<const float4*>(W + (size_t)(lane*4 + 3) * 4);
    float p0 = x0*w0.x + x1*w1.x + x2*w2.x + x3*w3.x;
    float p1 = x0*w0.y + x1*w1.y + x2*w2.y + x3*w3.y;
    float p2 = x0*w0.z + x1*w1.z + x2*w2.z + x3*w3.z;
    float p3 = x0*w0.w + x1*w1.w + x2*w2.w + x3*w3.w;
    #pragma unroll
    for (int off = 32; off > 0; off >>= 1) {
        p0 += __shfl_down(p0, off); p1 += __shfl_down(p1, off);
        p2 += __shfl_down(p2, off); p3 += __shfl_down(p3, off);
    }
    if (lane == 0) {
        const float o0 = p0 + bias[0], o1 = p1 + bias[1];
        const float o2 = p2 + bias[2], o3 = p3 + bias[3];
        *reinterpret_cast<float4*>(out + r * 4) = make_float4(o0, o1, o2, o3);
        const float4 g = *reinterpret_cast<const float4*>(tgt + r * 4);
        const float dx = o0 - g.x, dy = o1 - g.y, dz = o2 - g.z, dw = o3 - g.w;
        const float fm = 0.25f * (dx*dx + dy*dy + dz*dz + dw*dw);
        const float ma = fmaxf(fmaxf(fabsf(g.x), fabsf(g.y)), fmaxf(fabsf(g.z), fabsf(g.w)));
        const float mask = (ma > 0.f) ? 1.f : 0.f;
        const int b = (int)(r >> 9);
        pr[rr] = fm * mask / ((float)lens[b] * 64.f);
    }
    __syncthreads();
    if (threadIdx.x == 0)
        partials[blockIdx.x] = pr[0] + pr[1] + pr[2] + pr[3];
}

__global__ __launch_bounds__(256) void losssum_kernel(const float* __restrict__ partials,
                                                      float* __restrict__ lossp)
{
    __shared__ float red[256];
    float a = 0.f;
    for (int i = threadIdx.x; i < 8192; i += 256) a += partials[i];
    red[threadIdx.x] = a;
    __syncthreads();
    for (int st = 128; st > 0; st >>= 1) {
        if (threadIdx.x < st) red[threadIdx.x] += red[threadIdx.x + st];
        __syncthreads();
    }
    if (threadIdx.x == 0) *lossp = red[0];
}

__global__ void sentinel_kernel(float* __restrict__ out, int n)
{
    for (int i = blockIdx.x * 256 + threadIdx.x; i < n; i += gridDim.x * 256)
        out[i] = 1.0e9f;
}

extern "C" void kernel_launch(void* const* d_in, const int* in_sizes, int n_in,
                              void* d_out, int out_size, void* d_ws, size_t ws_size,
                              hipStream_t stream)
{
    const float* seq_in = (const float*)d_in[0];
    const float* tgt    = (const float*)d_in[1];
    const int*   lens   = (const int*)d_in[2];
    const float* W1  = (const float*)d_in[3];
    const float* b1  = (const float*)d_in[4];
    const float* W2  = (const float*)d_in[5];
    const float* b2  = (const float*)d_in[6];
    const float* Wd1 = (const float*)d_in[7];
    const float* bd1 = (const float*)d_in[8];
    const float* Wd2 = (const float*)d_in[9];
    const float* bd2 = (const float*)d_in[10];
    const float* Wd3 = (const float*)d_in[11];
    const float* bd3 = (const float*)d_in[12];
    const float* Wd4 = (const float*)d_in[13];
    const float* bd4 = (const float*)d_in[14];
    float* out = (float*)d_out;
    char* ws = (char*)d_ws;

    if (ws_size < WS_NEED) {
        hipLaunchKernelGGL(sentinel_kernel, dim3(256), dim3(256), 0, stream, out, out_size);
        return;
    }

    hipLaunchKernelGGL(prep_kernel, dim3((PN7 + 255) / 256), dim3(256), 0, stream,
                       seq_in, W1, b1, W2, b2, Wd1, Wd2, Wd3, ws);

    hipLaunchKernelGGL(persist_kernel, dim3(128), dim3(512), 0, stream, lens, ws);

    unsigned short* h2b = (unsigned short*)(ws + OFF_H2ALL);
    unsigned short* X1b = (unsigned short*)(ws + OFF_X1);
    unsigned short* X2b = h2b;   // h2all dead after D1
    unsigned short* X3b = X1b;   // X1 dead after D2
    const unsigned short* WD1P = (const unsigned short*)(ws + OFF_WD1P);
    const unsigned short* WD2P = (const unsigned short*)(ws + OFF_WD2P);
    const unsigned short* WD3P = (const unsigned short*)(ws + OFF_WD3P);
    float* partials = (float*)(ws + OFF_PART);

    hipLaunchKernelGGL(hgemm_kernel, dim3(8, 256), dim3(256), 0, stream,
                       h2b, WD1P, bd1, X1b, 512);
    hipLaunchKernelGGL(hgemm_kernel, dim3(8, 256), dim3(256), 0, stream,
                       X1b, WD2P, bd2, X2b, 512);
    hipLaunchKernelGGL(hgemm_kernel, dim3(4, 256), dim3(256), 0, stream,
                       X2b, WD3P, bd3, X3b, 256);
    hipLaunchKernelGGL(d4_kernel, dim3((Bn * Tn) / 4), dim3(256), 0, stream,
                       X3b, Wd4, bd4, tgt, lens, out, partials);
    hipLaunchKernelGGL(losssum_kernel, dim3(1), dim3(256), 0, stream,
                       partials, out + (size_t)Bn * Tn * 4);
}

// Round 14
// 1931.045 us; speedup vs baseline: 1.7496x; 1.7496x over previous
//
#include <hip/hip_runtime.h>
#include <hip/hip_bf16.h>

// ---------------- problem constants ----------------
constexpr int Bn = 64;
constexpr int Tn = 512;

using bf16x8 = __attribute__((ext_vector_type(8))) short;
using f32x4  = __attribute__((ext_vector_type(4))) float;
typedef unsigned long long u64;

// ---------------- ws layout (byte offsets) ----------------
// State is bf16 with LSB = 1-bit step tag (u64 = 4 tagged bf16, atomic store).
constexpr size_t OFF_H1    = 0;                       // bf16 [2][64][512] blended h1
constexpr size_t OFF_NH1   = 131072;                  // bf16 [16][64][512] nh1 (16-deep)
constexpr size_t OFF_H2S   = 1179648;                 // bf16 [2][64][512] blended h2
constexpr size_t OFF_L2P   = 1310720;                 // int [4][16] x 64B-strided L2 progress
constexpr size_t OFF_BIASP = 1318912;                 // f32 [2][2048] permuted biases
constexpr size_t OFF_H2ALL = 1335296;                 // bf16 [32768][512]
constexpr size_t OFF_X1    = OFF_H2ALL + 33554432;    // bf16 [32768][512]
constexpr size_t OFF_XPAD  = OFF_X1 + 33554432;       // bf16 [512][64][32]
constexpr size_t OFF_W1P   = OFF_XPAD + 2097152;      // bf16 [64][17][2][64][8]
constexpr size_t OFF_W2P   = OFF_W1P + 2228224;       // bf16 [64][32][2][64][8]
constexpr size_t OFF_WD1P  = OFF_W2P + 4194304;       // bf16 [32][16][64][8]
constexpr size_t OFF_WD2P  = OFF_WD1P + 524288;       // bf16 [32][16][64][8]
constexpr size_t OFF_WD3P  = OFF_WD2P + 524288;       // bf16 [16][16][64][8]
constexpr size_t OFF_PART  = OFF_WD3P + 262144;       // f32 [8192] loss partials
constexpr size_t WS_NEED   = OFF_PART + 32768;        // ~78 MB

constexpr u64 TAGM = 0x0001000100010001ULL;

__device__ __forceinline__ float sigf(float x) { return 1.f / (1.f + expf(-x)); }
__device__ __forceinline__ unsigned short f2b(float x) {
    __hip_bfloat16 h = __float2bfloat16(x);
    return *reinterpret_cast<unsigned short*>(&h);
}
__device__ __forceinline__ float b2f(unsigned short u) {
    unsigned v = ((unsigned)u) << 16;
    return *reinterpret_cast<float*>(&v);
}
__device__ __forceinline__ f32x4 mfma16(bf16x8 a, bf16x8 b, f32x4 c) {
    return __builtin_amdgcn_mfma_f32_16x16x32_bf16(a, b, c, 0, 0, 0);
}

// agent-scope relaxed atomics (R4-R13-proven primitives)
__device__ __forceinline__ u64 ld_agent_u64(const u64* p) {
    return __hip_atomic_load(p, __ATOMIC_RELAXED, __HIP_MEMORY_SCOPE_AGENT);
}
__device__ __forceinline__ void st_agent_u64(u64* p, u64 v) {
    __hip_atomic_store(p, v, __ATOMIC_RELAXED, __HIP_MEMORY_SCOPE_AGENT);
}
__device__ __forceinline__ int ldi(const int* p) {
    return __hip_atomic_load(p, __ATOMIC_RELAXED, __HIP_MEMORY_SCOPE_AGENT);
}
__device__ __forceinline__ void sti(int* p, int v) {
    __hip_atomic_store(p, v, __ATOMIC_RELAXED, __HIP_MEMORY_SCOPE_AGENT);
}
// block barrier WITHOUT vmem drain (no implicit vmcnt(0)): tagged stores
// stay in flight; consumers self-validate via tags.
__device__ __forceinline__ void block_sync_lds() {
    asm volatile("s_waitcnt lgkmcnt(0)" ::: "memory");
    __builtin_amdgcn_sched_barrier(0);
    __builtin_amdgcn_s_barrier();
}

// ---------------- one-time prep ----------------
constexpr int PN0 = 139264;            // W1P ushort8 items
constexpr int PN1 = PN0 + 262144;      // W2P
constexpr int PN2 = PN1 + 4096;        // BIASP f32 items
constexpr int PN3 = PN2 + 131072;      // XPAD ushort8
constexpr int PN4 = PN3 + 32768;       // WD1P ushort8
constexpr int PN5 = PN4 + 32768;       // WD2P
constexpr int PN6 = PN5 + 16384;       // WD3P
constexpr int PN7 = PN6 + 82432;       // init H1+NH1+H2S+L2P (float4 items)

__global__ __launch_bounds__(256) void prep_kernel(
    const float* __restrict__ seq_in,
    const float* __restrict__ W1, const float* __restrict__ b1,
    const float* __restrict__ W2, const float* __restrict__ b2,
    const float* __restrict__ Wd1, const float* __restrict__ Wd2,
    const float* __restrict__ Wd3, char* __restrict__ ws)
{
    const int idx = blockIdx.x * 256 + threadIdx.x;
    if (idx >= PN7) return;
    if (idx < PN0) {                       // W1P: [np][kk(17)][half][lane][8]
        const int lane = idx & 63; int r = idx >> 6;
        const int half = r & 1; r >>= 1;
        const int kk = r % 17, np = r / 17;
        const int colg = (np*2 + half)*16 + (lane & 15);
        const int oc = (colg & 3)*512 + (colg >> 2);
        const int lg = lane >> 4;
        short v[8];
        #pragma unroll
        for (int j = 0; j < 8; ++j) {
            float x;
            if (kk < 16) x = W1[(size_t)(6 + kk*32 + lg*8 + j) * 2048 + oc];
            else { const int rr = lg*8 + j; x = (rr < 6) ? W1[(size_t)rr * 2048 + oc] : 0.f; }
            v[j] = (short)f2b(x);
        }
        bf16x8* dst = (bf16x8*)((unsigned short*)(ws + OFF_W1P) + ((size_t)(np*17 + kk)*2 + half)*512 + lane*8);
        *dst = *(bf16x8*)v;
    } else if (idx < PN1) {                // W2P: [np][kk(32)][half][lane][8]
        const int i = idx - PN0;
        const int lane = i & 63; int r = i >> 6;
        const int half = r & 1; r >>= 1;
        const int kk = r & 31, np = r >> 5;
        const int colg = (np*2 + half)*16 + (lane & 15);
        const int oc = (colg & 3)*512 + (colg >> 2);
        const int lg = lane >> 4;
        short v[8];
        #pragma unroll
        for (int j = 0; j < 8; ++j)
            v[j] = (short)f2b(W2[(size_t)(kk*32 + lg*8 + j) * 2048 + oc]);
        bf16x8* dst = (bf16x8*)((unsigned short*)(ws + OFF_W2P) + ((size_t)(np*32 + kk)*2 + half)*512 + lane*8);
        *dst = *(bf16x8*)v;
    } else if (idx < PN2) {                // BIASP (gate-permuted)
        const int i = idx - PN1;
        const int layer = i >> 11, colg = i & 2047;
        const float* bb = layer ? b2 : b1;
        ((float*)(ws + OFF_BIASP))[i] = bb[(colg & 3)*512 + (colg >> 2)];
    } else if (idx < PN3) {                // XPAD [t][b][32]
        const int i = idx - PN2;
        const int sub = i & 3, tb = i >> 2;
        const int t = tb >> 6, b = tb & 63;
        short v[8];
        #pragma unroll
        for (int j = 0; j < 8; ++j) {
            const int rr = sub*8 + j;
            v[j] = (short)f2b(rr < 6 ? seq_in[((size_t)b*Tn + t)*6 + rr] : 0.f);
        }
        bf16x8* dst = (bf16x8*)((unsigned short*)(ws + OFF_XPAD) + (size_t)tb*32 + sub*8);
        *dst = *(bf16x8*)v;
    } else if (idx < PN6) {                // WD1P / WD2P / WD3P: [np][kk(16)][lane][8]
        int i; const float* Wd; size_t dsto; int N;
        if (idx < PN4)      { i = idx - PN3; Wd = Wd1; dsto = OFF_WD1P; N = 512; }
        else if (idx < PN5) { i = idx - PN4; Wd = Wd2; dsto = OFF_WD2P; N = 512; }
        else                { i = idx - PN5; Wd = Wd3; dsto = OFF_WD3P; N = 256; }
        const int lane = i & 63; const int r = i >> 6;
        const int kk = r & 15, np = r >> 4;
        const int col = np*16 + (lane & 15);
        const int lg = lane >> 4;
        short v[8];
        #pragma unroll
        for (int j = 0; j < 8; ++j)
            v[j] = (short)f2b(Wd[(size_t)(kk*32 + lg*8 + j) * N + col]);
        bf16x8* dst = (bf16x8*)((unsigned short*)(ws + dsto) + ((size_t)(np*16 + kk)*64 + lane)*8);
        *dst = *(bf16x8*)v;
    } else {                               // init tagged state + l2prog (CRITICAL for replay)
        const int i = idx - PN6;
        const size_t b = (size_t)i * 16;
        // H1 slot0 and H2S slot0 (the "tau=-2" slots) get LSB=1 (tiny denorm,
        // acts as 0) so they can't alias step-0's tag; everything else zero.
        unsigned fill = 0u;
        if (b < 65536 || (b >= OFF_H2S && b < OFF_H2S + 65536)) fill = 0x00010001u;
        int4 v4; v4.x = (int)fill; v4.y = (int)fill; v4.z = (int)fill; v4.w = (int)fill;
        ((int4*)(ws + OFF_H1))[i] = v4;
    }
}

// ---------------- persistent recurrence kernel ----------------
// 128 blocks x 512 threads (8 waves). Blocks 0..63: L1; 64..127: L2.
// mt = vb>>4 (batch 16-row group), ng = vb&15; wave w owns col-tile nt = ng*8+w.
// Sync: LSB-TAGGED bf16 state, drain-free, counter-free on the critical path.
//   tag(stored step τ) for H1/H2S = ((τ+1)>>1)&1 (2-slot ping-pong, peer skew
//   <= 1 proven); for NH1 = ((τ>>4)&1)^1 (16-deep, skew < 16 via lazy l2prog
//   back-pressure). Consumers spin on ONE data word, then load+verify all.
constexpr int FRAGS = 520;   // ushort stride per kk slot (1040 B)

__global__ __launch_bounds__(512, 1) void persist_kernel(const int* __restrict__ lens,
                                                         char* __restrict__ ws)
{
    __shared__ unsigned short afrag[33 * FRAGS];
    __shared__ float sc[8][16][17];

    const int tid = threadIdx.x;
    const int l = tid & 63, w = tid >> 6;
    const int blk = blockIdx.x;
    const bool isL1 = (blk < 64);
    const int vb = isL1 ? blk : blk - 64;
    const int mt = vb >> 4;
    const int ng = vb & 15;
    const int nt = ng * 8 + w;
    const int np = nt >> 1, half = nt & 1;
    const int lr = l & 15, lg = l >> 4;

    u64* H1u  = (u64*)(ws + OFF_H1);    // [2][64][128] u64
    u64* NH1u = (u64*)(ws + OFF_NH1);   // [16][64][128]
    u64* H2Su = (u64*)(ws + OFF_H2S);   // [2][64][128]
    int* l2prog = (int*)(ws + OFF_L2P); // stride 16 ints (64B)
    const float* biasp = (const float*)(ws + OFF_BIASP);
    u64* h2bu = (u64*)(ws + OFF_H2ALL);
    const unsigned short* XP = (const unsigned short*)(ws + OFF_XPAD);

    // ---- private W slice in VGPRs for all 512 steps ----
    bf16x8 wreg[32];
    if (isL1) {
        const unsigned short* Bp = (const unsigned short*)(ws + OFF_W1P)
                                 + ((size_t)(np*17)*2 + half)*512 + l*8;
        #pragma unroll
        for (int kk = 0; kk < 17; ++kk) wreg[kk] = *(const bf16x8*)(Bp + (size_t)kk*1024);
    } else {
        const unsigned short* Bp = (const unsigned short*)(ws + OFF_W2P)
                                 + ((size_t)(np*32)*2 + half)*512 + l*8;
        #pragma unroll
        for (int kk = 0; kk < 32; ++kk) wreg[kk] = *(const bf16x8*)(Bp + (size_t)kk*1024);
    }

    const int myb = mt*16 + lr;
    const int mylen = lens[myb];
    const float biascol = biasp[(isL1 ? 0 : 2048) + nt*16 + lr];
    float c_reg = 0.f, h_reg = 0.f;

    if (isL1) {
        const int g4 = tid & 127;          // my column-quad (u64 index within row)
        const int r0 = tid >> 7;           // rows r0 + it*4
        const int kk = g4 >> 3, sub = (g4 >> 1) & 3, hf = g4 & 1;
        const int* bpp = l2prog + (mt*16 + (tid & 15))*16;
        for (int t = 0; t < Tn; ++t) {
            // x-part staging (no dependence)
            if (tid < 64) {
                const int r = tid >> 2, lgg = tid & 3;
                bf16x8 xv = *(const bf16x8*)(XP + ((size_t)t*64 + mt*16 + r)*32 + lgg*8);
                *(bf16x8*)(afrag + 16*FRAGS + (lgg*16 + r)*8) = xv;
            }
            // lazy back-pressure every 8 steps: all L2 consumed nh1(t-8)
            // => writes t..t+7 overwrite NH1 slots t-16..t-9: all consumed
            if ((t & 7) == 0 && tid < 16) { while (ldi(bpp) < t - 8) {} }
            // ---- tag-poll h1(t-1): 1-word spin, then load-all + verify ----
            const u64 wt = (u64)((t >> 1) & 1);   // tag of stored step t-1
            const u64* src = H1u + (size_t)((t+1)&1)*8192 + (size_t)(mt*16)*128 + g4;
            const u64* pp0 = src + (size_t)r0*128;
            while ((ld_agent_u64(pp0) ^ wt) & 1ull) {}
            u64 v[4];
            for (;;) {
                #pragma unroll
                for (int it = 0; it < 4; ++it)
                    v[it] = ld_agent_u64(src + (size_t)(r0 + it*4)*128);
                u64 bad = 0;
                #pragma unroll
                for (int it = 0; it < 4; ++it) bad |= (v[it] ^ wt);
                if (!(bad & 1ull)) break;
            }
            #pragma unroll
            for (int it = 0; it < 4; ++it) {
                const u64 cv = v[it] & ~TAGM;      // clear tag bits
                *(u64*)(afrag + kk*FRAGS + (sub*16 + r0 + it*4)*8 + hf*4) = cv;
            }
            block_sync_lds();

            f32x4 acc = {0.f,0.f,0.f,0.f};
            const unsigned short* ap = afrag + l*8;
            #pragma unroll
            for (int kk2 = 0; kk2 < 17; ++kk2)
                acc = mfma16(*(const bf16x8*)(ap + kk2*FRAGS), wreg[kk2], acc);

            #pragma unroll
            for (int i = 0; i < 4; ++i) sc[w][lg*4 + i][lr] = acc[i] + biascol;
            asm volatile("s_waitcnt lgkmcnt(0)" ::: "memory");

            const float gi = sc[w][lr][lg*4+0], gj = sc[w][lr][lg*4+1];
            const float gf = sc[w][lr][lg*4+2], go = sc[w][lr][lg*4+3];
            const float m = (t < mylen) ? 1.f : 0.f;
            const float cnew = c_reg*sigf(gf + 1.f) + sigf(gi)*tanhf(gj);
            c_reg = m*cnew + (1.f - m)*c_reg;
            const float nh = tanhf(cnew)*sigf(go);
            const float hb = m*nh + (1.f - m)*h_reg;
            h_reg = hb;

            // publish tagged values — NO drain, tags carry ordering
            const int sv = ((int)f2b(hb) << 16) | (int)f2b(nh);
            const int g0 = __shfl(sv, lr), g1 = __shfl(sv, lr+16),
                      g2 = __shfl(sv, lr+32), g3 = __shfl(sv, lr+48);
            if (lg == 0) {
                u64 hbp = (u64)(((unsigned)g0 >> 16) | (((unsigned)g1 >> 16) << 16))
                        | ((u64)(((unsigned)g2 >> 16) | (((unsigned)g3 >> 16) << 16)) << 32);
                u64 nhp = (u64)(unsigned)((g0 & 0xffff) | ((g1 & 0xffff) << 16))
                        | ((u64)(unsigned)((g2 & 0xffff) | ((g3 & 0xffff) << 16)) << 32);
                const u64 tH = (u64)(((t+1) >> 1) & 1);
                const u64 tN = (u64)(((t >> 4) & 1) ^ 1);
                hbp = (hbp & ~TAGM) | (tH ? TAGM : 0ull);
                nhp = (nhp & ~TAGM) | (tN ? TAGM : 0ull);
                st_agent_u64(H1u  + (size_t)(t&1)*8192  + (size_t)myb*128 + nt, hbp);
                st_agent_u64(NH1u + (size_t)(t&15)*8192 + (size_t)myb*128 + nt, nhp);
            }
            block_sync_lds();   // afrag/sc reuse fence (no vmcnt drain)
        }
    } else {
        const int g4 = tid & 255;          // g4<128: nh1 quad; else h2 quad g4-128
        const int r0 = tid >> 8;           // rows r0 + it*2
        const int kk = g4 >> 3, sub = (g4 >> 1) & 3, hf = g4 & 1;
        for (int s = 0; s < Tn; ++s) {
            const u64 wt = (g4 < 128) ? (u64)(((s >> 4) & 1) ^ 1)   // nh1(s)
                                      : (u64)((s >> 1) & 1);        // h2(s-1)
            const u64* src = (g4 < 128)
                ? (NH1u + (size_t)(s&15)*8192 + (size_t)(mt*16)*128 + g4)
                : (H2Su + (size_t)((s+1)&1)*8192 + (size_t)(mt*16)*128 + (g4-128));
            const u64* pp0 = src + (size_t)r0*128;
            while ((ld_agent_u64(pp0) ^ wt) & 1ull) {}
            u64 v[8];
            for (;;) {
                #pragma unroll
                for (int it = 0; it < 8; ++it)
                    v[it] = ld_agent_u64(src + (size_t)(r0 + it*2)*128);
                u64 bad = 0;
                #pragma unroll
                for (int it = 0; it < 8; ++it) bad |= (v[it] ^ wt);
                if (!(bad & 1ull)) break;
            }
            #pragma unroll
            for (int it = 0; it < 8; ++it) {
                const u64 cv = v[it] & ~TAGM;
                *(u64*)(afrag + kk*FRAGS + (sub*16 + r0 + it*2)*8 + hf*4) = cv;
            }
            block_sync_lds();
            if (tid == 0) sti(l2prog + (mt*16 + ng)*16, s + 1);  // consumed nh1(s)

            f32x4 acc = {0.f,0.f,0.f,0.f};
            const unsigned short* ap = afrag + l*8;
            #pragma unroll
            for (int kk2 = 0; kk2 < 32; ++kk2)
                acc = mfma16(*(const bf16x8*)(ap + kk2*FRAGS), wreg[kk2], acc);

            #pragma unroll
            for (int i = 0; i < 4; ++i) sc[w][lg*4 + i][lr] = acc[i] + biascol;
            asm volatile("s_waitcnt lgkmcnt(0)" ::: "memory");

            const float gi = sc[w][lr][lg*4+0], gj = sc[w][lr][lg*4+1];
            const float gf = sc[w][lr][lg*4+2], go = sc[w][lr][lg*4+3];
            const float m = (s < mylen) ? 1.f : 0.f;
            const float cnew = c_reg*sigf(gf + 1.f) + sigf(gi)*tanhf(gj);
            c_reg = m*cnew + (1.f - m)*c_reg;
            const float nh = tanhf(cnew)*sigf(go);
            const float hb = m*nh + (1.f - m)*h_reg;
            h_reg = hb;

            const int sv = ((int)f2b(hb) << 16) | (int)f2b(m*nh);
            const int g0 = __shfl(sv, lr), g1 = __shfl(sv, lr+16),
                      g2 = __shfl(sv, lr+32), g3 = __shfl(sv, lr+48);
            if (lg == 0) {
                u64 hbp = (u64)(((unsigned)g0 >> 16) | (((unsigned)g1 >> 16) << 16))
                        | ((u64)(((unsigned)g2 >> 16) | (((unsigned)g3 >> 16) << 16)) << 32);
                u64 nhp = (u64)(unsigned)((g0 & 0xffff) | ((g1 & 0xffff) << 16))
                        | ((u64)(unsigned)((g2 & 0xffff) | ((g3 & 0xffff) << 16)) << 32);
                const u64 tH = (u64)(((s+1) >> 1) & 1);
                hbp = (hbp & ~TAGM) | (tH ? TAGM : 0ull);
                st_agent_u64(H2Su + (size_t)(s&1)*8192 + (size_t)myb*128 + nt, hbp);
                h2bu[((size_t)myb*Tn + s)*128 + nt] = nhp;   // cached packed (head input)
            }
            block_sync_lds();   // afrag/sc reuse fence (no vmcnt drain)
        }
    }
}

// ---------------- head GEMM: C = relu(A[M,512]bf16 @ WP + bias) -> bf16 ----------------
__global__ __launch_bounds__(256) void hgemm_kernel(
    const unsigned short* __restrict__ A, const unsigned short* __restrict__ WP,
    const float* __restrict__ bias, unsigned short* __restrict__ C, int N)
{
    __shared__ unsigned short tr[4][16][24];
    const int tid = threadIdx.x;
    const int l = tid & 63, w = tid >> 6;
    const int np = blockIdx.x * 4 + w;
    const int colbase = np * 16;
    const int lr = l & 15, lg = l >> 4;

    bf16x8 wfr[16];
    #pragma unroll
    for (int kk = 0; kk < 16; ++kk)
        wfr[kk] = *(const bf16x8*)(WP + ((size_t)(np*16 + kk)*64 + l)*8);
    const float bv = bias[colbase + lr];

    for (int i = 0; i < 8; ++i) {
        const int rt = blockIdx.y * 8 + i;
        const unsigned short* ap = A + (size_t)(rt*16 + lr)*512 + lg*8;
        f32x4 acc = {0.f,0.f,0.f,0.f};
        #pragma unroll
        for (int kk = 0; kk < 16; ++kk)
            acc = mfma16(*(const bf16x8*)(ap + kk*32), wfr[kk], acc);
        #pragma unroll
        for (int j = 0; j < 4; ++j)
            tr[w][lg*4 + j][lr] = f2b(fmaxf(acc[j] + bv, 0.f));
        asm volatile("s_waitcnt lgkmcnt(0)" ::: "memory");
        if (lg == 0) {
            bf16x8 r0 = *(const bf16x8*)&tr[w][lr][0];
            bf16x8 r1 = *(const bf16x8*)&tr[w][lr][8];
            unsigned short* cp = C + (size_t)(rt*16 + lr)*N + colbase;
            *(bf16x8*)cp = r0;
            *(bf16x8*)(cp + 8) = r1;
        }
        asm volatile("s_waitcnt lgkmcnt(0)" ::: "memory");
    }
}

// ---------------- final layer + loss partials ----------------
__global__ __launch_bounds__(256) void d4_kernel(
    const unsigned short* __restrict__ X3, const float* __restrict__ W,
    const float* __restrict__ bias, const float* __restrict__ tgt,
    const int* __restrict__ lens, float* __restrict__ out,
    float* __restrict__ partials)
{
    __shared__ float pr[4];
    const int lane = threadIdx.x & 63;
    const int rr = threadIdx.x >> 6;
    const size_t r = (size_t)blockIdx.x * 4 + rr;
    const u64 xv = *(const u64*)(X3 + r * 256 + lane * 4);
    const float x0 = b2f((unsigned short)(xv & 0xffff));
    const float x1 = b2f((unsigned short)((xv >> 16) & 0xffff));
    const float x2 = b2f((unsigned short)((xv >> 32) & 0xffff));
    const float x3 = b2f((unsigned short)((xv >> 48) & 0xffff));
    const float4 w0 = *reinterpret_cast<const float4*>(W + (size_t)(lane*4 + 0) * 4);
    const float4 w1 = *reinterpret_cast<const float4*>(W + (size_t)(lane*4 + 1) * 4);
    const float4 w2 = *reinterpret_cast<const float4*>(W + (size_t)(lane*4 + 2) * 4);
    const float4 w3 = *reinterpret_cast<const float4*>(W + (size_t)(lane*4 + 3) * 4);
    float p0 = x0*w0.x + x1*w1.x + x2*w2.x + x3*w3.x;
    float p1 = x0*w0.y + x1*w1.y + x2*w2.y + x3*w3.y;
    float p2 = x0*w0.z + x1*w1.z + x2*w2.z + x3*w3.z;
    float p3 = x0*w0.w + x1*w1.w + x2*w2.w + x3*w3.w;
    #pragma unroll
    for (int off = 32; off > 0; off >>= 1) {
        p0 += __shfl_down(p0, off); p1 += __shfl_down(p1, off);
        p2 += __shfl_down(p2, off); p3 += __shfl_down(p3, off);
    }
    if (lane == 0) {
        const float o0 = p0 + bias[0], o1 = p1 + bias[1];
        const float o2 = p2 + bias[2], o3 = p3 + bias[3];
        *reinterpret_cast<float4*>(out + r * 4) = make_float4(o0, o1, o2, o3);
        const float4 g = *reinterpret_cast<const float4*>(tgt + r * 4);
        const float dx = o0 - g.x, dy = o1 - g.y, dz = o2 - g.z, dw = o3 - g.w;
        const float fm = 0.25f * (dx*dx + dy*dy + dz*dz + dw*dw);
        const float ma = fmaxf(fmaxf(fabsf(g.x), fabsf(g.y)), fmaxf(fabsf(g.z), fabsf(g.w)));
        const float mask = (ma > 0.f) ? 1.f : 0.f;
        const int b = (int)(r >> 9);
        pr[rr] = fm * mask / ((float)lens[b] * 64.f);
    }
    __syncthreads();
    if (threadIdx.x == 0)
        partials[blockIdx.x] = pr[0] + pr[1] + pr[2] + pr[3];
}

__global__ __launch_bounds__(256) void losssum_kernel(const float* __restrict__ partials,
                                                      float* __restrict__ lossp)
{
    __shared__ float red[256];
    float a = 0.f;
    for (int i = threadIdx.x; i < 8192; i += 256) a += partials[i];
    red[threadIdx.x] = a;
    __syncthreads();
    for (int st = 128; st > 0; st >>= 1) {
        if (threadIdx.x < st) red[threadIdx.x] += red[threadIdx.x + st];
        __syncthreads();
    }
    if (threadIdx.x == 0) *lossp = red[0];
}

__global__ void sentinel_kernel(float* __restrict__ out, int n)
{
    for (int i = blockIdx.x * 256 + threadIdx.x; i < n; i += gridDim.x * 256)
        out[i] = 1.0e9f;
}

extern "C" void kernel_launch(void* const* d_in, const int* in_sizes, int n_in,
                              void* d_out, int out_size, void* d_ws, size_t ws_size,
                              hipStream_t stream)
{
    const float* seq_in = (const float*)d_in[0];
    const float* tgt    = (const float*)d_in[1];
    const int*   lens   = (const int*)d_in[2];
    const float* W1  = (const float*)d_in[3];
    const float* b1  = (const float*)d_in[4];
    const float* W2  = (const float*)d_in[5];
    const float* b2  = (const float*)d_in[6];
    const float* Wd1 = (const float*)d_in[7];
    const float* bd1 = (const float*)d_in[8];
    const float* Wd2 = (const float*)d_in[9];
    const float* bd2 = (const float*)d_in[10];
    const float* Wd3 = (const float*)d_in[11];
    const float* bd3 = (const float*)d_in[12];
    const float* Wd4 = (const float*)d_in[13];
    const float* bd4 = (const float*)d_in[14];
    float* out = (float*)d_out;
    char* ws = (char*)d_ws;

    if (ws_size < WS_NEED) {
        hipLaunchKernelGGL(sentinel_kernel, dim3(256), dim3(256), 0, stream, out, out_size);
        return;
    }

    hipLaunchKernelGGL(prep_kernel, dim3((PN7 + 255) / 256), dim3(256), 0, stream,
                       seq_in, W1, b1, W2, b2, Wd1, Wd2, Wd3, ws);

    hipLaunchKernelGGL(persist_kernel, dim3(128), dim3(512), 0, stream, lens, ws);

    unsigned short* h2b = (unsigned short*)(ws + OFF_H2ALL);
    unsigned short* X1b = (unsigned short*)(ws + OFF_X1);
    unsigned short* X2b = h2b;   // h2all dead after D1
    unsigned short* X3b = X1b;   // X1 dead after D2
    const unsigned short* WD1P = (const unsigned short*)(ws + OFF_WD1P);
    const unsigned short* WD2P = (const unsigned short*)(ws + OFF_WD2P);
    const unsigned short* WD3P = (const unsigned short*)(ws + OFF_WD3P);
    float* partials = (float*)(ws + OFF_PART);

    hipLaunchKernelGGL(hgemm_kernel, dim3(8, 256), dim3(256), 0, stream,
                       h2b, WD1P, bd1, X1b, 512);
    hipLaunchKernelGGL(hgemm_kernel, dim3(8, 256), dim3(256), 0, stream,
                       X1b, WD2P, bd2, X2b, 512);
    hipLaunchKernelGGL(hgemm_kernel, dim3(4, 256), dim3(256), 0, stream,
                       X2b, WD3P, bd3, X3b, 256);
    hipLaunchKernelGGL(d4_kernel, dim3((Bn * Tn) / 4), dim3(256), 0, stream,
                       X3b, Wd4, bd4, tgt, lens, out, partials);
    hipLaunchKernelGGL(losssum_kernel, dim3(1), dim3(256), 0, stream,
                       partials, out + (size_t)Bn * Tn * 4);
}